// Round 4
// baseline (419.819 us; speedup 1.0000x reference)
//
#include <hip/hip_runtime.h>

#define BB 512
#define NN 256
#define SS 128
#define MM 64
#define UNFOLDS 6
#define BT2 16    // batches per block
#define JT2 32    // columns per block

static constexpr float EPS_ = 1e-8f;
static constexpr float L2E = 1.4426950408889634f;

// LDS (floats): pac[NN*JT2] float2 (16K f) | pw[NN*JT2] (8K f) | ssn[512] | ssd[512]
//             | vt[BT2*NN] (4K f, doubles as xt[BT2*SS]) | redN[7*128] f4 | redD[7*128] f4
// total = 16384+8192+512+512+4096+3584+3584 = 36864 floats = 144 KiB

__global__ __launch_bounds__(1024) void ltc_fused(
    const float* __restrict__ x, const float* __restrict__ state,
    const float* __restrict__ gl, const float* __restrict__ rp,
    const float* __restrict__ cap,
    const float* __restrict__ w, const float* __restrict__ sg,
    const float* __restrict__ mu, const float* __restrict__ E,
    const float* __restrict__ sw, const float* __restrict__ ssg,
    const float* __restrict__ smu, const float* __restrict__ sE,
    const float* __restrict__ mask, const float* __restrict__ smask,
    const float* __restrict__ iw, const float* __restrict__ ib,
    const float* __restrict__ ow, const float* __restrict__ ob,
    float* __restrict__ out, unsigned* __restrict__ bar,
    float* __restrict__ vb0, float* __restrict__ vb1) {
  extern __shared__ float lds[];
  float2* pac = (float2*)lds;                    // {a, c} per (i, jl)
  float*  pw  = lds + 2 * NN * JT2;              // wE  (|wE| = wm)
  float*  ssn = pw + NN * JT2;
  float*  ssd = ssn + BT2 * JT2;
  float*  vt  = ssd + BT2 * JT2;                 // [BT2][NN]; sensory: xt[BT2][SS]
  float4* redN = (float4*)(vt + BT2 * NN);
  float4* redD = redN + 7 * 128;

  int tid = threadIdx.x;
  int jt = blockIdx.x & 7;
  int bt = blockIdx.x >> 3;
  int jbase = jt * JT2;
  int bbase = bt * BT2;
  int j = tid & 31;
  int quad = (tid >> 5) & 3;     // 4 batches each
  int split = tid >> 7;          // 8-way reduction split
  int b0 = quad * 4;
  int jcol = jbase + j;
  int t = tid & 127;

  // ---- phase 0: fold recurrent params into LDS ----
  // gate = 1/(1+exp2(a*v + c)); a = -sigma*log2e; c = sigma*mu*log2e
#pragma unroll
  for (int k = 0; k < 8; ++k) {
    int e = tid + k * 1024;
    int i = e >> 5;
    int jl = e & 31;
    int gidx = i * NN + jbase + jl;
    float a = sg[gidx] * L2E;
    float wm = w[gidx] * mask[gidx];
    pac[e] = make_float2(-a, a * mu[gidx]);
    pw[e] = wm * E[gidx];        // wm = |wE| (w*mask >= 0, E = ±1)
  }
  // stage x tile (xt overlays vt region)
  ((float2*)vt)[tid] = ((const float2*)(x + bbase * SS))[tid];
  __syncthreads();

  // ---- phase 1: sensory aggregation (block-local) ----
  {
    float n[4] = {0, 0, 0, 0}, d[4] = {0, 0, 0, 0};
#pragma unroll 4
    for (int si = 0; si < SS / 8; ++si) {
      int s = split * (SS / 8) + si;
      int gs = s * NN + jcol;
      float a = ssg[gs] * L2E;
      float wm = sw[gs] * smask[gs];
      float wE = wm * sE[gs];
      float aS = -a * iw[s];
      float cS = a * (smu[gs] - ib[s]);
#pragma unroll
      for (int q = 0; q < 4; ++q) {
        float v = vt[(b0 + q) * SS + s];
        float e1 = __builtin_amdgcn_exp2f(fmaf(aS, v, cS));
        float g = __builtin_amdgcn_rcpf(1.0f + e1);
        n[q] = fmaf(wE, g, n[q]);
        d[q] = fmaf(wm, g, d[q]);
      }
    }
    if (split) {
      redN[(split - 1) * 128 + t] = make_float4(n[0], n[1], n[2], n[3]);
      redD[(split - 1) * 128 + t] = make_float4(d[0], d[1], d[2], d[3]);
    }
    __syncthreads();
    if (split == 0) {
#pragma unroll
      for (int k = 0; k < 7; ++k) {
        float4 rn = redN[k * 128 + t], rd = redD[k * 128 + t];
        n[0] += rn.x; n[1] += rn.y; n[2] += rn.z; n[3] += rn.w;
        d[0] += rd.x; d[1] += rd.y; d[2] += rd.z; d[3] += rd.w;
      }
#pragma unroll
      for (int q = 0; q < 4; ++q) {
        ssn[(b0 + q) * JT2 + j] = n[q];
        ssd[(b0 + q) * JT2 + j] = d[q];
      }
    }
  }

  float cmt = cap[jcol] * (float)UNFOLDS;
  float glv = gl[jcol];
  float base = glv * rp[jcol];
  unsigned* ctr = bar + bt * 32;   // 128-B spaced counter per batch-tile group

  // ---- phases 2..7: unfolds ----
  for (int u = 0; u < UNFOLDS; ++u) {
    const float* src = (u == 0) ? state : ((u & 1) ? vb1 : vb0);
    float* dst = (u & 1) ? vb0 : vb1;
    __syncthreads();   // prior phase's LDS reads done; safe to overwrite vt/red
    ((float4*)vt)[tid] = ((const float4*)(src + bbase * NN))[tid];
    __syncthreads();
    float n[4] = {0, 0, 0, 0}, d[4] = {0, 0, 0, 0};
#pragma unroll 4
    for (int ii = 0; ii < 32; ++ii) {
      int i = split * 32 + ii;
      int pidx = i * JT2 + j;
      float2 ac = pac[pidx];
      float wE = pw[pidx];
      float wm = __builtin_fabsf(wE);
#pragma unroll
      for (int q = 0; q < 4; ++q) {
        float v = vt[(b0 + q) * NN + i];
        float e1 = __builtin_amdgcn_exp2f(fmaf(ac.x, v, ac.y));
        float g = __builtin_amdgcn_rcpf(1.0f + e1);
        n[q] = fmaf(wE, g, n[q]);
        d[q] = fmaf(wm, g, d[q]);
      }
    }
    if (split) {
      redN[(split - 1) * 128 + t] = make_float4(n[0], n[1], n[2], n[3]);
      redD[(split - 1) * 128 + t] = make_float4(d[0], d[1], d[2], d[3]);
    }
    __syncthreads();
    if (split == 0) {
#pragma unroll
      for (int k = 0; k < 7; ++k) {
        float4 rn = redN[k * 128 + t], rd = redD[k * 128 + t];
        n[0] += rn.x; n[1] += rn.y; n[2] += rn.z; n[3] += rn.w;
        d[0] += rd.x; d[1] += rd.y; d[2] += rd.z; d[3] += rd.w;
      }
#pragma unroll
      for (int q = 0; q < 4; ++q) {
        int b = bbase + b0 + q;
        float num = fmaf(cmt, vt[(b0 + q) * NN + jcol], base) + n[q] + ssn[(b0 + q) * JT2 + j];
        float den = cmt + glv + d[q] + ssd[(b0 + q) * JT2 + j] + EPS_;
        float vn = num * __builtin_amdgcn_rcpf(den);
        if (u < UNFOLDS - 1) {
          dst[b * NN + jcol] = vn;
        } else {
          out[BB * MM + b * NN + jcol] = vn;                       // v output
          if (jcol < MM) out[b * MM + jcol] = fmaf(vn, ow[jcol], ob[jcol]);
        }
      }
    }
    if (u < UNFOLDS - 1) {
      // 8-block group barrier (blocks sharing this batch-tile)
      __threadfence();      // writers: drain global stores (device scope)
      __syncthreads();
      if (tid == 0) {
        __hip_atomic_fetch_add(ctr, 1u, __ATOMIC_RELEASE, __HIP_MEMORY_SCOPE_AGENT);
        unsigned target = 8u * (unsigned)(u + 1);   // monotonic, no reset needed
        while (__hip_atomic_load(ctr, __ATOMIC_ACQUIRE, __HIP_MEMORY_SCOPE_AGENT) < target)
          __builtin_amdgcn_s_sleep(2);
      }
      __syncthreads();
    }
  }
}

extern "C" void kernel_launch(void* const* d_in, const int* in_sizes, int n_in,
                              void* d_out, int out_size, void* d_ws, size_t ws_size,
                              hipStream_t stream) {
  const float* x     = (const float*)d_in[0];
  const float* state = (const float*)d_in[1];
  const float* gl    = (const float*)d_in[2];
  const float* rp    = (const float*)d_in[3];
  const float* cap   = (const float*)d_in[4];
  const float* w     = (const float*)d_in[5];
  const float* sg    = (const float*)d_in[6];
  const float* mu    = (const float*)d_in[7];
  const float* E     = (const float*)d_in[8];
  const float* sw    = (const float*)d_in[9];
  const float* ssg   = (const float*)d_in[10];
  const float* smu   = (const float*)d_in[11];
  const float* sE    = (const float*)d_in[12];
  const float* mask  = (const float*)d_in[13];
  const float* smask = (const float*)d_in[14];
  const float* iw    = (const float*)d_in[15];
  const float* ib    = (const float*)d_in[16];
  const float* ow    = (const float*)d_in[17];
  const float* ob    = (const float*)d_in[18];

  unsigned* bar = (unsigned*)d_ws;                       // 32 groups x 128 B
  float* vb0 = (float*)((char*)d_ws + 4096);             // B*N
  float* vb1 = vb0 + BB * NN;
  float* fout = (float*)d_out;

  static const size_t smem = (size_t)(2 * NN * JT2 + NN * JT2 + 2 * BT2 * JT2 +
                                      BT2 * NN + 2 * 7 * 128 * 4) * 4;  // 147456 B
  hipFuncSetAttribute((const void*)ltc_fused,
                      hipFuncAttributeMaxDynamicSharedMemorySize, (int)smem);

  hipMemsetAsync(d_ws, 0, 4096, stream);  // zero barrier counters (deterministic)
  ltc_fused<<<dim3(256), dim3(1024), smem, stream>>>(
      x, state, gl, rp, cap, w, sg, mu, E, sw, ssg, smu, sE, mask, smask,
      iw, ib, ow, ob, fout, bar, vb0, vb1);
}

// Round 5
// 130.837 us; speedup vs baseline: 3.2087x; 3.2087x over previous
//
#include <hip/hip_runtime.h>

#define BB 512
#define NN 256
#define SS 128
#define MM 64
#define UNFOLDS 6

static constexpr float EPS_ = 1e-8f;
static constexpr float L2E = 1.4426950408889634f;

// ---------------- prep: column-compact active (mask!=0) entries ----------------
// Recurrent (blocks 0..255, col=bid): entries i with mask[i][col]!=0 ->
//   pac[r*NN+col]={-a, a*mu}, pwc[r*NN+col]=w*mask*E, idxc[r*NN+col]=i, cnt[col]=#active
// Sensory (blocks 256..511): same over s, with input affine folded:
//   a' = -a*iw[s], c' = a*(smu - ib[s])
__global__ __launch_bounds__(256) void prep_compact(
    const float* __restrict__ w, const float* __restrict__ sg,
    const float* __restrict__ mu, const float* __restrict__ E,
    const float* __restrict__ mask,
    const float* __restrict__ sw, const float* __restrict__ ssg,
    const float* __restrict__ smu, const float* __restrict__ sE,
    const float* __restrict__ smask,
    const float* __restrict__ iw, const float* __restrict__ ib,
    float2* __restrict__ pac, float* __restrict__ pwc,
    unsigned char* __restrict__ idxc, int* __restrict__ cnt,
    float2* __restrict__ spac, float* __restrict__ spwc,
    unsigned char* __restrict__ sidx, int* __restrict__ scnt) {
  int col = blockIdx.x & 255;
  bool sens = blockIdx.x >= 256;
  int i = threadIdx.x;
  int lane = i & 63;
  int wv = i >> 6;
  __shared__ int wtot[4];
  bool active = false;
  float2 ac = make_float2(0.f, 0.f);
  float wE = 0.f;
  if (!sens) {
    int g = i * NN + col;
    float m = mask[g];
    active = (m != 0.0f);
    float a = sg[g] * L2E;
    ac = make_float2(-a, a * mu[g]);
    wE = w[g] * m * E[g];
  } else if (i < SS) {
    int g = i * NN + col;
    float m = smask[g];
    active = (m != 0.0f);
    float a = ssg[g] * L2E;
    ac = make_float2(-a * iw[i], a * (smu[g] - ib[i]));
    wE = sw[g] * m * sE[g];
  }
  unsigned long long bal = __ballot(active);
  if (lane == 63) wtot[wv] = __popcll(bal);
  __syncthreads();
  int base = 0;
  for (int k = 0; k < wv; ++k) base += wtot[k];
  int total = wtot[0] + wtot[1] + wtot[2] + wtot[3];
  if (active) {
    int r = base + __popcll(bal & ((1ull << lane) - 1ull));
    int o = r * NN + col;
    if (!sens) { pac[o] = ac; pwc[o] = wE; idxc[o] = (unsigned char)i; }
    else       { spac[o] = ac; spwc[o] = wE; sidx[o] = (unsigned char)i; }
  }
  if (i == 0) { if (!sens) cnt[col] = total; else scnt[col] = total; }
}

// ---------------- main: one block = 2 batches x all 256 columns, all 6 unfolds ----------------
// 1024 threads: j = tid&255 (column), split = tid>>8 (4-way strided over the active list).
// v kept in LDS across unfolds; params streamed (compacted) from L2; no cross-block deps.
__global__ __launch_bounds__(1024) void ltc_main(
    const float* __restrict__ x, const float* __restrict__ state,
    const float* __restrict__ gl, const float* __restrict__ rp,
    const float* __restrict__ cap,
    const float* __restrict__ ow, const float* __restrict__ ob,
    const float2* __restrict__ pac, const float* __restrict__ pwc,
    const unsigned char* __restrict__ idxc, const int* __restrict__ cnt,
    const float2* __restrict__ spac, const float* __restrict__ spwc,
    const unsigned char* __restrict__ sidx, const int* __restrict__ scnt,
    float* __restrict__ out) {
  __shared__ float v0[2][NN], v1[2][NN];        // 4 KiB
  __shared__ float ssn[2][NN], ssd[2][NN];      // 4 KiB
  __shared__ float redN[4][2][NN];              // 8 KiB
  __shared__ float redD[4][2][NN];              // 8 KiB
  __shared__ float xt[2][SS];                   // 1 KiB
  int tid = threadIdx.x;
  int j = tid & 255;
  int split = tid >> 8;
  int bbase = blockIdx.x * 2;

  if (tid < 2 * SS) xt[tid >> 7][tid & 127] = x[bbase * SS + tid];
  else if (tid < 2 * SS + 2 * NN) {
    int t = tid - 2 * SS;
    v0[t >> 8][t & 255] = state[bbase * NN + t];
  }
  __syncthreads();

  // ---- sensory aggregation (block-local) ----
  {
    int kc = scnt[j];
    float n0 = 0, d0 = 0, n1 = 0, d1 = 0;
    for (int k = split; k < kc; k += 4) {
      int off = k * NN + j;
      float2 ac = spac[off];
      float wE = spwc[off];
      int s = sidx[off];
      float wm = __builtin_fabsf(wE);
      float ga = __builtin_amdgcn_rcpf(1.f + __builtin_amdgcn_exp2f(fmaf(ac.x, xt[0][s], ac.y)));
      float gb = __builtin_amdgcn_rcpf(1.f + __builtin_amdgcn_exp2f(fmaf(ac.x, xt[1][s], ac.y)));
      n0 = fmaf(wE, ga, n0); d0 = fmaf(wm, ga, d0);
      n1 = fmaf(wE, gb, n1); d1 = fmaf(wm, gb, d1);
    }
    redN[split][0][j] = n0; redN[split][1][j] = n1;
    redD[split][0][j] = d0; redD[split][1][j] = d1;
    __syncthreads();
    if (tid < 512) {
      int b = tid >> 8, jj = tid & 255;
      ssn[b][jj] = redN[0][b][jj] + redN[1][b][jj] + redN[2][b][jj] + redN[3][b][jj];
      ssd[b][jj] = redD[0][b][jj] + redD[1][b][jj] + redD[2][b][jj] + redD[3][b][jj];
    }
    __syncthreads();
  }

  int kr = cnt[j];
  float cmt = 0, glv = 0, base_ = 0;
  if (tid < 512) {
    int jj = tid & 255;
    cmt = cap[jj] * (float)UNFOLDS;
    glv = gl[jj];
    base_ = glv * rp[jj];
  }

  // ---- 6 unfolds, v ping-pongs in LDS ----
  for (int u = 0; u < UNFOLDS; ++u) {
    const float (*vc)[NN] = (u & 1) ? v1 : v0;
    float (*vn_)[NN] = (u & 1) ? v0 : v1;
    float n0 = 0, d0 = 0, n1 = 0, d1 = 0;
#pragma unroll 4
    for (int k = split; k < kr; k += 4) {
      int off = k * NN + j;
      float2 ac = pac[off];
      float wE = pwc[off];
      int i = idxc[off];
      float wm = __builtin_fabsf(wE);
      float va = vc[0][i], vb = vc[1][i];
      float ga = __builtin_amdgcn_rcpf(1.f + __builtin_amdgcn_exp2f(fmaf(ac.x, va, ac.y)));
      float gb = __builtin_amdgcn_rcpf(1.f + __builtin_amdgcn_exp2f(fmaf(ac.x, vb, ac.y)));
      n0 = fmaf(wE, ga, n0); d0 = fmaf(wm, ga, d0);
      n1 = fmaf(wE, gb, n1); d1 = fmaf(wm, gb, d1);
    }
    redN[split][0][j] = n0; redN[split][1][j] = n1;
    redD[split][0][j] = d0; redD[split][1][j] = d1;
    __syncthreads();
    if (tid < 512) {
      int b = tid >> 8, jj = tid & 255;
      float n = ssn[b][jj] + redN[0][b][jj] + redN[1][b][jj] + redN[2][b][jj] + redN[3][b][jj];
      float d = ssd[b][jj] + redD[0][b][jj] + redD[1][b][jj] + redD[2][b][jj] + redD[3][b][jj];
      float num = fmaf(cmt, vc[b][jj], base_) + n;
      float den = cmt + glv + d + EPS_;
      float vv = num * __builtin_amdgcn_rcpf(den);
      vn_[b][jj] = vv;
      if (u == UNFOLDS - 1) {
        out[BB * MM + (bbase + b) * NN + jj] = vv;                   // v output
        if (jj < MM) out[(bbase + b) * MM + jj] = fmaf(vv, ow[jj], ob[jj]);
      }
    }
    __syncthreads();
  }
}

extern "C" void kernel_launch(void* const* d_in, const int* in_sizes, int n_in,
                              void* d_out, int out_size, void* d_ws, size_t ws_size,
                              hipStream_t stream) {
  const float* x     = (const float*)d_in[0];
  const float* state = (const float*)d_in[1];
  const float* gl    = (const float*)d_in[2];
  const float* rp    = (const float*)d_in[3];
  const float* cap   = (const float*)d_in[4];
  const float* w     = (const float*)d_in[5];
  const float* sg    = (const float*)d_in[6];
  const float* mu    = (const float*)d_in[7];
  const float* E     = (const float*)d_in[8];
  const float* sw    = (const float*)d_in[9];
  const float* ssg   = (const float*)d_in[10];
  const float* smu   = (const float*)d_in[11];
  const float* sE    = (const float*)d_in[12];
  const float* mask  = (const float*)d_in[13];
  const float* smask = (const float*)d_in[14];
  const float* iw    = (const float*)d_in[15];
  const float* ib    = (const float*)d_in[16];
  const float* ow    = (const float*)d_in[17];
  const float* ob    = (const float*)d_in[18];

  char* p = (char*)d_ws;
  float2* pac  = (float2*)p;                 p += (size_t)NN * NN * 8;   // 512 KiB
  float2* spac = (float2*)p;                 p += (size_t)SS * NN * 8;   // 256 KiB
  float*  pwc  = (float*)p;                  p += (size_t)NN * NN * 4;   // 256 KiB
  float*  spwc = (float*)p;                  p += (size_t)SS * NN * 4;   // 128 KiB
  int*    cnt  = (int*)p;                    p += (size_t)NN * 4;
  int*    scnt = (int*)p;                    p += (size_t)NN * 4;
  unsigned char* idxc = (unsigned char*)p;   p += (size_t)NN * NN;
  unsigned char* sidx = (unsigned char*)p;   p += (size_t)SS * NN;

  float* fout = (float*)d_out;  // [B*M out][B*N v]

  prep_compact<<<512, 256, 0, stream>>>(
      w, sg, mu, E, mask, sw, ssg, smu, sE, smask, iw, ib,
      pac, pwc, idxc, cnt, spac, spwc, sidx, scnt);
  ltc_main<<<BB / 2, 1024, 0, stream>>>(
      x, state, gl, rp, cap, ow, ob,
      pac, pwc, idxc, cnt, spac, spwc, sidx, scnt, fout);
}

// Round 6
// 90.313 us; speedup vs baseline: 4.6485x; 1.4487x over previous
//
#include <hip/hip_runtime.h>
#include <hip/hip_fp16.h>

#define BB 512
#define NN 256
#define SS 128
#define MM 64
#define UNFOLDS 6

static constexpr float EPS_ = 1e-8f;
static constexpr float L2E = 1.4426950408889634f;

// ---------- prep: fold params, pack {a,c} as half2 (4B) + wE f32 (4B) ----------
// gate = 1/(1+exp2(a*v + c)); a = -sigma*log2e; c = sigma*mu*log2e
// sensory folds input affine: a' = -a*iw[s], c' = a*(smu - ib[s])
__global__ __launch_bounds__(256) void prep_dense(
    const float* __restrict__ w, const float* __restrict__ sg,
    const float* __restrict__ mu, const float* __restrict__ E,
    const float* __restrict__ mask,
    const float* __restrict__ sw, const float* __restrict__ ssg,
    const float* __restrict__ smu, const float* __restrict__ sE,
    const float* __restrict__ smask,
    const float* __restrict__ iw, const float* __restrict__ ib,
    __half2* __restrict__ ach, float* __restrict__ wEf,
    __half2* __restrict__ sach, float* __restrict__ swEf) {
  int idx = blockIdx.x * 256 + threadIdx.x;
  if (idx < NN * NN) {
    float a = sg[idx] * L2E;
    ach[idx] = __floats2half2_rn(-a, a * mu[idx]);
    wEf[idx] = w[idx] * mask[idx] * E[idx];
  } else {
    int e = idx - NN * NN;  // < SS*NN
    int s = e >> 8;
    float a = ssg[e] * L2E;
    sach[e] = __floats2half2_rn(-a * iw[s], a * (smu[e] - ib[s]));
    swEf[e] = sw[e] * smask[e] * sE[e];
  }
}

// ---------- main: one block = 2 batches x all 256 columns, all unfolds ----------
// 1024 threads: j = tid&255 (column), split = tid>>8 (4-way over i).
// Dense inner loop: compile-time bounds, linear coalesced param loads,
// wave-uniform i -> LDS broadcast v reads (no conflicts, no divergence).
__global__ __launch_bounds__(1024) void ltc_dense(
    const float* __restrict__ x, const float* __restrict__ state,
    const float* __restrict__ gl, const float* __restrict__ rp,
    const float* __restrict__ cap,
    const float* __restrict__ ow, const float* __restrict__ ob,
    const __half2* __restrict__ ach, const float* __restrict__ wEf,
    const __half2* __restrict__ sach, const float* __restrict__ swEf,
    float* __restrict__ out) {
  __shared__ float v0[2][NN], v1[2][NN];        // 4 KiB
  __shared__ float xt[2][SS];                   // 1 KiB
  __shared__ float ssn[2][NN], ssd[2][NN];      // 4 KiB
  __shared__ float redN[3][2][NN];              // 6 KiB
  __shared__ float redD[3][2][NN];              // 6 KiB
  int tid = threadIdx.x;
  int j = tid & 255;
  int split = tid >> 8;
  int bbase = blockIdx.x * 2;

  if (tid < 2 * SS) {
    xt[tid >> 7][tid & 127] = x[bbase * SS + tid];
  } else if (tid < 2 * SS + 2 * NN) {
    int t = tid - 2 * SS;
    v0[t >> 8][t & 255] = state[bbase * NN + t];
  }
  __syncthreads();

  // ---- sensory aggregation ----
  {
    float n0 = 0, d0 = 0, n1 = 0, d1 = 0;
#pragma unroll 8
    for (int k = 0; k < SS / 4; ++k) {
      int s = split * (SS / 4) + k;
      int off = s * NN + j;
      float2 ac = __half22float2(sach[off]);
      float wE = swEf[off];
      float wm = __builtin_fabsf(wE);
      float va = xt[0][s], vb = xt[1][s];
      float ga = __builtin_amdgcn_rcpf(1.f + __builtin_amdgcn_exp2f(fmaf(ac.x, va, ac.y)));
      float gb = __builtin_amdgcn_rcpf(1.f + __builtin_amdgcn_exp2f(fmaf(ac.x, vb, ac.y)));
      n0 = fmaf(wE, ga, n0); d0 = fmaf(wm, ga, d0);
      n1 = fmaf(wE, gb, n1); d1 = fmaf(wm, gb, d1);
    }
    if (split) {
      redN[split - 1][0][j] = n0; redN[split - 1][1][j] = n1;
      redD[split - 1][0][j] = d0; redD[split - 1][1][j] = d1;
    }
    __syncthreads();
    if (split == 0) {
#pragma unroll
      for (int k = 0; k < 3; ++k) {
        n0 += redN[k][0][j]; n1 += redN[k][1][j];
        d0 += redD[k][0][j]; d1 += redD[k][1][j];
      }
      ssn[0][j] = n0; ssn[1][j] = n1;
      ssd[0][j] = d0; ssd[1][j] = d1;
    }
    __syncthreads();
  }

  float cmt = cap[j] * (float)UNFOLDS;
  float glv = gl[j];
  float base_ = glv * rp[j];

  // ---- 6 unfolds, v ping-pongs in LDS, zero cross-block traffic ----
  for (int u = 0; u < UNFOLDS; ++u) {
    const float (*vc)[NN] = (u & 1) ? v1 : v0;
    float (*vn_)[NN] = (u & 1) ? v0 : v1;
    float n0 = 0, d0 = 0, n1 = 0, d1 = 0;
#pragma unroll 8
    for (int ii = 0; ii < NN / 4; ++ii) {
      int i = split * (NN / 4) + ii;
      int off = i * NN + j;
      float2 ac = __half22float2(ach[off]);
      float wE = wEf[off];
      float wm = __builtin_fabsf(wE);
      float va = vc[0][i], vb = vc[1][i];   // wave-uniform i -> LDS broadcast
      float ga = __builtin_amdgcn_rcpf(1.f + __builtin_amdgcn_exp2f(fmaf(ac.x, va, ac.y)));
      float gb = __builtin_amdgcn_rcpf(1.f + __builtin_amdgcn_exp2f(fmaf(ac.x, vb, ac.y)));
      n0 = fmaf(wE, ga, n0); d0 = fmaf(wm, ga, d0);
      n1 = fmaf(wE, gb, n1); d1 = fmaf(wm, gb, d1);
    }
    if (split) {
      redN[split - 1][0][j] = n0; redN[split - 1][1][j] = n1;
      redD[split - 1][0][j] = d0; redD[split - 1][1][j] = d1;
    }
    __syncthreads();
    if (split == 0) {
#pragma unroll
      for (int k = 0; k < 3; ++k) {
        n0 += redN[k][0][j]; n1 += redN[k][1][j];
        d0 += redD[k][0][j]; d1 += redD[k][1][j];
      }
      float num0 = fmaf(cmt, vc[0][j], base_) + n0 + ssn[0][j];
      float den0 = cmt + glv + d0 + ssd[0][j] + EPS_;
      float va = num0 * __builtin_amdgcn_rcpf(den0);
      float num1 = fmaf(cmt, vc[1][j], base_) + n1 + ssn[1][j];
      float den1 = cmt + glv + d1 + ssd[1][j] + EPS_;
      float vb = num1 * __builtin_amdgcn_rcpf(den1);
      vn_[0][j] = va;
      vn_[1][j] = vb;
      if (u == UNFOLDS - 1) {
        out[BB * MM + (bbase + 0) * NN + j] = va;
        out[BB * MM + (bbase + 1) * NN + j] = vb;
        if (j < MM) {
          out[(bbase + 0) * MM + j] = fmaf(va, ow[j], ob[j]);
          out[(bbase + 1) * MM + j] = fmaf(vb, ow[j], ob[j]);
        }
      }
    }
    __syncthreads();
  }
}

extern "C" void kernel_launch(void* const* d_in, const int* in_sizes, int n_in,
                              void* d_out, int out_size, void* d_ws, size_t ws_size,
                              hipStream_t stream) {
  const float* x     = (const float*)d_in[0];
  const float* state = (const float*)d_in[1];
  const float* gl    = (const float*)d_in[2];
  const float* rp    = (const float*)d_in[3];
  const float* cap   = (const float*)d_in[4];
  const float* w     = (const float*)d_in[5];
  const float* sg    = (const float*)d_in[6];
  const float* mu    = (const float*)d_in[7];
  const float* E     = (const float*)d_in[8];
  const float* sw    = (const float*)d_in[9];
  const float* ssg   = (const float*)d_in[10];
  const float* smu   = (const float*)d_in[11];
  const float* sE    = (const float*)d_in[12];
  const float* mask  = (const float*)d_in[13];
  const float* smask = (const float*)d_in[14];
  const float* iw    = (const float*)d_in[15];
  const float* ib    = (const float*)d_in[16];
  const float* ow    = (const float*)d_in[17];
  const float* ob    = (const float*)d_in[18];

  char* p = (char*)d_ws;
  __half2* ach  = (__half2*)p;   p += (size_t)NN * NN * 4;   // 256 KiB
  __half2* sach = (__half2*)p;   p += (size_t)SS * NN * 4;   // 128 KiB
  float*   wEf  = (float*)p;     p += (size_t)NN * NN * 4;   // 256 KiB
  float*   swEf = (float*)p;     p += (size_t)SS * NN * 4;   // 128 KiB

  float* fout = (float*)d_out;  // [B*M out][B*N v]

  prep_dense<<<(NN * NN + SS * NN) / 256, 256, 0, stream>>>(
      w, sg, mu, E, mask, sw, ssg, smu, sE, smask, iw, ib,
      ach, wEf, sach, swEf);
  ltc_dense<<<BB / 2, 1024, 0, stream>>>(
      x, state, gl, rp, cap, ow, ob, ach, wEf, sach, swEf, fout);
}